// Round 14
// baseline (807.770 us; speedup 1.0000x reference)
//
#include <hip/hip_runtime.h>
#include <hip/hip_fp16.h>
#include <hip/hip_fp8.h>
#include <cstdint>

// B=64, T=512, F=1024, U=256, G=4U=1024
#define BB 64
#define TT 512
#define FF 1024
#define UU 256
#define GG 1024

typedef _Float16 f16x8 __attribute__((ext_vector_type(8)));
typedef float f32x4 __attribute__((ext_vector_type(4)));
typedef int i32x8 __attribute__((ext_vector_type(8)));

typedef union { uint4 u4[2]; i32x8 v; } pk32;  // 32 fp8 = one K=128 MFMA operand

__device__ __forceinline__ float sigmf_(float x) { return 1.f / (1.f + __expf(-x)); }
__device__ __forceinline__ float tanhf_(float x) { return 1.f - 2.f / (1.f + __expf(2.f * x)); }

// ---------------- mask kernel: mask[b,t] = any(x[b,t,:] != 0) ----------------
__global__ __launch_bounds__(256) void mask_kernel(const float* __restrict__ x,
                                                   float* __restrict__ maskF) {
  int row = blockIdx.x;
  int tid = threadIdx.x;
  const float4* xr = (const float4*)(x + (size_t)row * FF);
  float4 v = xr[tid];
  bool nz = (v.x != 0.f) || (v.y != 0.f) || (v.z != 0.f) || (v.w != 0.f);
  __shared__ int flag;
  if (tid == 0) flag = 0;
  __syncthreads();
  if (__any(nz)) {
    if ((tid & 63) == 0) atomicOr(&flag, 1);
  }
  __syncthreads();
  if (tid == 0) maskF[row] = flag ? 1.f : 0.f;
}

// ---- pack W_h (256x1024 f32, [u][c]) -> whP [1024 cols][256 k] fp8 e4m3 -----
__global__ __launch_bounds__(256) void pack_whP(const float* __restrict__ Wh,
                                                uint8_t* __restrict__ whP) {
  int col = blockIdx.x;   // 0..1023
  int k = threadIdx.x;    // 0..255
  __hip_fp8_e4m3 f(Wh[(size_t)k * GG + col] * 16.f);
  whP[col * 256 + k] = (uint8_t)f.__x;
}

// ---------------- MFMA GEMM: C(f16) = [relu](A @ B + bias) -------------------
template <typename TA, bool RELU, bool PERM>
__global__ __launch_bounds__(256) void gemm16(const TA* __restrict__ A,
                                              const float* __restrict__ Bm,
                                              const float* __restrict__ bias,
                                              __half* __restrict__ C,
                                              int M, int N, int K) {
  __shared__ _Float16 As[128][40];
  __shared__ _Float16 Bs[64][40];
  int tid = threadIdx.x;
  int lane = tid & 63, w = tid >> 6;
  int wm = w & 1, wn = w >> 1;
  int m0 = blockIdx.x * 128, n0 = blockIdx.y * 64;
  int fr = lane & 15, ks = lane >> 4;

  f32x4 acc[4][2];
#pragma unroll
  for (int i = 0; i < 4; ++i)
#pragma unroll
    for (int j = 0; j < 2; ++j) acc[i][j] = (f32x4){0.f, 0.f, 0.f, 0.f};

  for (int k0 = 0; k0 < K; k0 += 32) {
    {
      int r = tid >> 3, kq = (tid & 7) * 4;
#pragma unroll
      for (int i = 0; i < 4; ++i) {
        int row = r + 32 * i;
        const TA* src = A + (size_t)(m0 + row) * K + k0 + kq;
        if constexpr (sizeof(TA) == 4) {
          float4 v = *reinterpret_cast<const float4*>(src);
          union { uint2 u; _Float16 h[4]; } pk;
          pk.h[0] = (_Float16)v.x; pk.h[1] = (_Float16)v.y;
          pk.h[2] = (_Float16)v.z; pk.h[3] = (_Float16)v.w;
          *reinterpret_cast<uint2*>(&As[row][kq]) = pk.u;
        } else {
          uint2 v = *reinterpret_cast<const uint2*>(src);
          *reinterpret_cast<uint2*>(&As[row][kq]) = v;
        }
      }
      int nn = tid & 63, kb = tid >> 6;
#pragma unroll
      for (int i = 0; i < 8; ++i) {
        int kk = kb + 4 * i;
        Bs[nn][kk] = (_Float16)Bm[(size_t)(k0 + kk) * N + n0 + nn];
      }
    }
    __syncthreads();
    f16x8 af[4], bf[2];
#pragma unroll
    for (int fm = 0; fm < 4; ++fm)
      af[fm] = *reinterpret_cast<const f16x8*>(&As[wm * 64 + fm * 16 + fr][ks * 8]);
#pragma unroll
    for (int fn = 0; fn < 2; ++fn)
      bf[fn] = *reinterpret_cast<const f16x8*>(&Bs[wn * 32 + fn * 16 + fr][ks * 8]);
#pragma unroll
    for (int fm = 0; fm < 4; ++fm)
#pragma unroll
      for (int fn = 0; fn < 2; ++fn)
        acc[fm][fn] = __builtin_amdgcn_mfma_f32_16x16x32_f16(af[fm], bf[fn], acc[fm][fn], 0, 0, 0);
    __syncthreads();
  }
#pragma unroll
  for (int fm = 0; fm < 4; ++fm)
#pragma unroll
    for (int fn = 0; fn < 2; ++fn) {
      int mg0 = m0 + wm * 64 + fm * 16 + ks * 4;
      int ng = n0 + wn * 32 + fn * 16 + fr;
      float bv = bias[ng];
      int ngs = PERM ? ((ng & 255) * 4 + (ng >> 8)) : ng;
#pragma unroll
      for (int r = 0; r < 4; ++r) {
        float v = acc[fm][fn][r] + bv;
        if constexpr (RELU) v = fmaxf(v, 0.f);
        C[(size_t)(mg0 + r) * N + ngs] = __float2half(v);
      }
    }
}

// ------------- recurrence: MX fp8 K=128 MFMA, TWO batches per block ----------
// 512 threads = 8 waves = 2/SIMD; budget 256 regs/thread (R13-verified law).
// M-dim amortization: A-fragment rows 0-7 carry hA, rows 8-15 carry hB
// (A-operand row = lane&15 -> lanes fr<8 read hA, fr>=8 read hB; k-slice
// addressing identical to the R11-13 refcheck-verified broadcast form).
// The SAME 128 MFMAs/step and the SAME register-resident weights now serve
// TWO sequences. D rows 0/8: q in {0,1} -> batch A, q in {2,3} -> batch B
// (row = q*4 + reg, reg 0). Each thread cell-updates 2 cols of its batch.
__attribute__((amdgpu_waves_per_eu(2, 2)))
__global__ void __launch_bounds__(512, 1)
lstm_rec(const uint8_t* __restrict__ whP,   // [1024][256] fp8 (x16)
         const __half* __restrict__ zxi,    // [B*T][256u][4gate] f16
         const float* __restrict__ maskF,   // [B*T]
         const float* __restrict__ Wp,      // [256]
         __half* __restrict__ ppG)          // [B*T][256] f16: h*wp per col
{
  __shared__ __align__(16) uint8_t hA[2][256];   // fp8 h, batch A (ping-pong)
  __shared__ __align__(16) uint8_t hB[2][256];   // fp8 h, batch B
  __shared__ float mldsA[TT];                    // 2KB mask row A
  __shared__ float mldsB[TT];                    // 2KB mask row B

  const int b0 = blockIdx.x * 2, b1 = b0 + 1;
  const int t = threadIdx.x;
  const int lane = t & 63, w = t >> 6;       // 8 waves
  const int fr = lane & 15, q = lane >> 4;
  const int SC1 = 0x7F7F7F7F;                // E8M0 x1.0 scales
  const bool isA = (q < 2);                  // this thread's cell batch
  const bool wr = ((q & 1) == 0);            // q==0 / q==2 do the writes

  const uint4* whP4 = (const uint4*)whP;  // uint4 idx = col*16 + kt*8 + q*2

  // --- preload ALL weight B-frags: kt 0..1, tile T = g*2+j (8 tiles) ---
  pk32 bfr[2][8];
#pragma unroll
  for (int kt = 0; kt < 2; ++kt)
#pragma unroll
    for (int g = 0; g < 4; ++g)
#pragma unroll
      for (int j = 0; j < 2; ++j) {
        int col = g * 256 + w * 32 + j * 16 + fr;
        bfr[kt][g * 2 + j].u4[0] = whP4[col * 16 + kt * 8 + q * 2];
        bfr[kt][g * 2 + j].u4[1] = whP4[col * 16 + kt * 8 + q * 2 + 1];
      }
#pragma unroll
  for (int kt = 0; kt < 2; ++kt)
#pragma unroll
    for (int T = 0; T < 8; ++T) {
      asm volatile("" : "+v"(bfr[kt][T].u4[0].x), "+v"(bfr[kt][T].u4[0].y),
                        "+v"(bfr[kt][T].u4[0].z), "+v"(bfr[kt][T].u4[0].w));
      asm volatile("" : "+v"(bfr[kt][T].u4[1].x), "+v"(bfr[kt][T].u4[1].y),
                        "+v"(bfr[kt][T].u4[1].z), "+v"(bfr[kt][T].u4[1].w));
    }

  if (t < 64) { ((uint32_t*)hA[0])[t] = 0u; ((uint32_t*)hB[0])[t] = 0u; }
  mldsA[t] = maskF[b0 * TT + t];
  mldsB[t] = maskF[b1 * TT + t];

  // this thread's two cell columns (same for both j-tiles)
  const int u0 = w * 32 + fr;        // j = 0
  const int u1 = w * 32 + 16 + fr;   // j = 1
  float c0 = 0.f, h0 = 0.f, c1 = 0.f, h1 = 0.f;
  float wp0 = Wp[u0], wp1 = Wp[u1];
  __syncthreads();

  const int myb = isA ? b0 : b1;
  const uint2* zp = (const uint2*)(zxi + (size_t)myb * TT * GG);
  __half* ppp = ppG + (size_t)myb * TT * UU;

  uint2 zx_c0 = zp[u0], zx_c1 = zp[u1];
  __half pp0 = __float2half(0.f), pp1 = __float2half(0.f);

  int p = 0;
  for (int step = 0; step < TT; ++step) {
    // deferred store of previous step's pp
    if (step > 0 && wr) {
      ppp[(size_t)(step - 1) * UU + u0] = pp0;
      ppp[(size_t)(step - 1) * UU + u1] = pp1;
    }
    // issue next step's zx loads; consumed next iteration
    const uint2* zq = zp + ((step + 1 < TT) ? (size_t)(step + 1) * 256 : (size_t)step * 256);
    uint2 zx_n0 = zq[u0], zx_n1 = zq[u1];
    float mval = isA ? mldsA[step] : mldsB[step];

    // ---- MFMA phase: A-rows split by fr (rows 0-7 = hA, 8-15 = hB) ----
    const uint4* hsrc = (const uint4*)((fr < 8) ? hA[p] : hB[p]);
    pk32 a0, a1;
    a0.u4[0] = hsrc[q * 2];     a0.u4[1] = hsrc[q * 2 + 1];
    a1.u4[0] = hsrc[8 + q * 2]; a1.u4[1] = hsrc[8 + q * 2 + 1];
    f32x4 d[8];
#pragma unroll
    for (int T = 0; T < 8; ++T) {
      f32x4 z = {0.f, 0.f, 0.f, 0.f};
      z = __builtin_amdgcn_mfma_scale_f32_16x16x128_f8f6f4(
          a0.v, bfr[0][T].v, z, 0, 0, 0, SC1, 0, SC1);
      d[T] = __builtin_amdgcn_mfma_scale_f32_16x16x128_f8f6f4(
          a1.v, bfr[1][T].v, z, 0, 0, 0, SC1, 0, SC1);
    }
    // D row = q*4 + reg; reg 0 -> rows {0,4,8,12}: q<2 = batch A, q>=2 = B.
    float si0 = d[0][0], si1 = d[1][0];   // gate i, cols u0/u1
    float sf0 = d[2][0], sf1 = d[3][0];   // gate f
    float sg0 = d[4][0], sg1 = d[5][0];   // gate g
    float so0 = d[6][0], so1 = d[7][0];   // gate o

    // ---- cell phase: 2 cols per thread, independent chains (ILP) ----
    {
      union { uint2 u2; __half2 h2[2]; } za, zb;
      za.u2 = zx_c0; zb.u2 = zx_c1;
      float2 zif0 = __half22float2(za.h2[0]), zgo0 = __half22float2(za.h2[1]);
      float2 zif1 = __half22float2(zb.h2[0]), zgo1 = __half22float2(zb.h2[1]);
      float gi0 = fmaf(si0, 0.0625f, zif0.x), gi1 = fmaf(si1, 0.0625f, zif1.x);
      float gf0 = fmaf(sf0, 0.0625f, zif0.y), gf1 = fmaf(sf1, 0.0625f, zif1.y);
      float gg0 = fmaf(sg0, 0.0625f, zgo0.x), gg1 = fmaf(sg1, 0.0625f, zgo1.x);
      float go0 = fmaf(so0, 0.0625f, zgo0.y), go1 = fmaf(so1, 0.0625f, zgo1.y);
      float ig0 = sigmf_(gi0), ig1 = sigmf_(gi1);
      float fg0 = sigmf_(gf0), fg1 = sigmf_(gf1);
      float g_0 = tanhf_(gg0), g_1 = tanhf_(gg1);
      float og0 = sigmf_(go0), og1 = sigmf_(go1);
      float cn0 = fg0 * c0 + ig0 * g_0, cn1 = fg1 * c1 + ig1 * g_1;
      float hn0 = og0 * tanhf_(cn0), hn1 = og1 * tanhf_(cn1);
      bool on = (mval > 0.5f);
      c0 = on ? cn0 : c0; h0 = on ? hn0 : h0;
      c1 = on ? cn1 : c1; h1 = on ? hn1 : h1;
      __hip_fp8_e4m3 f80(h0), f81(h1);
      if (wr) {
        uint8_t* hdst = isA ? hA[p ^ 1] : hB[p ^ 1];
        hdst[u0] = (uint8_t)f80.__x;
        hdst[u1] = (uint8_t)f81.__x;
      }
      pp0 = __float2half(h0 * wp0);
      pp1 = __float2half(h1 * wp1);
    }
    // raw barrier: order LDS (h ping-pong); VMEM stays in flight.
    asm volatile("s_waitcnt lgkmcnt(0)" ::: "memory");
    __builtin_amdgcn_s_barrier();
    asm volatile("" ::: "memory");
    p ^= 1;
    zx_c0 = zx_n0; zx_c1 = zx_n1;
  }
  if (wr) {
    ppp[(size_t)(TT - 1) * UU + u0] = pp0;
    ppp[(size_t)(TT - 1) * UU + u1] = pp1;
  }
}

// --------- projection: out[row] = sigmoid(sum_u ppG[row][u] + bp) ------------
__global__ __launch_bounds__(256) void proj_kernel(const __half* __restrict__ ppG,
                                                   const float* __restrict__ bp,
                                                   float* __restrict__ out) {
  int row = blockIdx.x * 4 + (threadIdx.x >> 6);
  int lane = threadIdx.x & 63;
  const ushort4* pr = (const ushort4*)(ppG + (size_t)row * UU);
  ushort4 v = pr[lane];
  __half2 a = *reinterpret_cast<__half2*>(&v.x);
  __half2 c = *reinterpret_cast<__half2*>(&v.z);
  float2 af = __half22float2(a), cf = __half22float2(c);
  float s = af.x + af.y + cf.x + cf.y;
#pragma unroll
  for (int off = 32; off > 0; off >>= 1) s += __shfl_down(s, off);
  if (lane == 0) out[row] = 1.f / (1.f + __expf(-(s + bp[0])));
}

extern "C" void kernel_launch(void* const* d_in, const int* in_sizes, int n_in,
                              void* d_out, int out_size, void* d_ws, size_t ws_size,
                              hipStream_t stream) {
  const float* x = (const float*)d_in[0];
  const float* Wfc = (const float*)d_in[1];
  const float* bfc = (const float*)d_in[2];
  const float* Wx = (const float*)d_in[3];
  const float* Wh = (const float*)d_in[4];
  const float* blstm = (const float*)d_in[5];
  const float* Wp = (const float*)d_in[6];
  const float* bp = (const float*)d_in[7];
  float* out = (float*)d_out;

  char* ws = (char*)d_ws;
  float* maskF = (float*)(ws);                                   // 128 KB
  __half* zh = (__half*)(ws + 131072);                           // 16.78 MB
  __half* zxi = (__half*)(ws + 131072 + 16777216);               // 67.1 MB
  uint8_t* whP = (uint8_t*)(ws + 131072 + 16777216 + 67108864);  // 256 KB
  __half* ppG = zh;  // zh is dead after gemm_zx; exact size match (16.78 MB)

  mask_kernel<<<BB * TT, 256, 0, stream>>>(x, maskF);
  pack_whP<<<GG, 256, 0, stream>>>(Wh, whP);
  gemm16<float, true, false><<<dim3((BB * TT) / 128, UU / 64), 256, 0, stream>>>(
      x, Wfc, bfc, zh, BB * TT, UU, FF);
  gemm16<__half, false, true><<<dim3((BB * TT) / 128, GG / 64), 256, 0, stream>>>(
      zh, Wx, blstm, zxi, BB * TT, GG, UU);
  lstm_rec<<<BB / 2, 512, 0, stream>>>(whP, zxi, maskF, Wp, ppG);
  proj_kernel<<<(BB * TT) / 4, 256, 0, stream>>>(ppG, bp, out);
}

// Round 15
// 666.258 us; speedup vs baseline: 1.2124x; 1.2124x over previous
//
#include <hip/hip_runtime.h>
#include <hip/hip_fp16.h>
#include <hip/hip_fp8.h>
#include <cstdint>

// B=64, T=512, F=1024, U=256, G=4U=1024
#define BB 64
#define TT 512
#define FF 1024
#define UU 256
#define GG 1024

typedef _Float16 f16x8 __attribute__((ext_vector_type(8)));
typedef float f32x4 __attribute__((ext_vector_type(4)));
typedef int i32x8 __attribute__((ext_vector_type(8)));

typedef union { uint4 u4[2]; i32x8 v; } pk32;  // 32 fp8 = one K=128 MFMA operand

__device__ __forceinline__ float sigmf_(float x) { return 1.f / (1.f + __expf(-x)); }
__device__ __forceinline__ float tanhf_(float x) { return 1.f - 2.f / (1.f + __expf(2.f * x)); }

// ---------------- mask kernel: mask[b,t] = any(x[b,t,:] != 0) ----------------
__global__ __launch_bounds__(256) void mask_kernel(const float* __restrict__ x,
                                                   float* __restrict__ maskF) {
  int row = blockIdx.x;
  int tid = threadIdx.x;
  const float4* xr = (const float4*)(x + (size_t)row * FF);
  float4 v = xr[tid];
  bool nz = (v.x != 0.f) || (v.y != 0.f) || (v.z != 0.f) || (v.w != 0.f);
  __shared__ int flag;
  if (tid == 0) flag = 0;
  __syncthreads();
  if (__any(nz)) {
    if ((tid & 63) == 0) atomicOr(&flag, 1);
  }
  __syncthreads();
  if (tid == 0) maskF[row] = flag ? 1.f : 0.f;
}

// ---- pack W_h (256x1024 f32, [u][c]) -> whP [1024 cols][256 k] fp8 e4m3 -----
__global__ __launch_bounds__(256) void pack_whP(const float* __restrict__ Wh,
                                                uint8_t* __restrict__ whP) {
  int col = blockIdx.x;   // 0..1023
  int k = threadIdx.x;    // 0..255
  __hip_fp8_e4m3 f(Wh[(size_t)k * GG + col] * 16.f);
  whP[col * 256 + k] = (uint8_t)f.__x;
}

// ---------------- MFMA GEMM: C(f16) = [relu](A @ B + bias) -------------------
template <typename TA, bool RELU, bool PERM>
__global__ __launch_bounds__(256) void gemm16(const TA* __restrict__ A,
                                              const float* __restrict__ Bm,
                                              const float* __restrict__ bias,
                                              __half* __restrict__ C,
                                              int M, int N, int K) {
  __shared__ _Float16 As[128][40];
  __shared__ _Float16 Bs[64][40];
  int tid = threadIdx.x;
  int lane = tid & 63, w = tid >> 6;
  int wm = w & 1, wn = w >> 1;
  int m0 = blockIdx.x * 128, n0 = blockIdx.y * 64;
  int fr = lane & 15, ks = lane >> 4;

  f32x4 acc[4][2];
#pragma unroll
  for (int i = 0; i < 4; ++i)
#pragma unroll
    for (int j = 0; j < 2; ++j) acc[i][j] = (f32x4){0.f, 0.f, 0.f, 0.f};

  for (int k0 = 0; k0 < K; k0 += 32) {
    {
      int r = tid >> 3, kq = (tid & 7) * 4;
#pragma unroll
      for (int i = 0; i < 4; ++i) {
        int row = r + 32 * i;
        const TA* src = A + (size_t)(m0 + row) * K + k0 + kq;
        if constexpr (sizeof(TA) == 4) {
          float4 v = *reinterpret_cast<const float4*>(src);
          union { uint2 u; _Float16 h[4]; } pk;
          pk.h[0] = (_Float16)v.x; pk.h[1] = (_Float16)v.y;
          pk.h[2] = (_Float16)v.z; pk.h[3] = (_Float16)v.w;
          *reinterpret_cast<uint2*>(&As[row][kq]) = pk.u;
        } else {
          uint2 v = *reinterpret_cast<const uint2*>(src);
          *reinterpret_cast<uint2*>(&As[row][kq]) = v;
        }
      }
      int nn = tid & 63, kb = tid >> 6;
#pragma unroll
      for (int i = 0; i < 8; ++i) {
        int kk = kb + 4 * i;
        Bs[nn][kk] = (_Float16)Bm[(size_t)(k0 + kk) * N + n0 + nn];
      }
    }
    __syncthreads();
    f16x8 af[4], bf[2];
#pragma unroll
    for (int fm = 0; fm < 4; ++fm)
      af[fm] = *reinterpret_cast<const f16x8*>(&As[wm * 64 + fm * 16 + fr][ks * 8]);
#pragma unroll
    for (int fn = 0; fn < 2; ++fn)
      bf[fn] = *reinterpret_cast<const f16x8*>(&Bs[wn * 32 + fn * 16 + fr][ks * 8]);
#pragma unroll
    for (int fm = 0; fm < 4; ++fm)
#pragma unroll
      for (int fn = 0; fn < 2; ++fn)
        acc[fm][fn] = __builtin_amdgcn_mfma_f32_16x16x32_f16(af[fm], bf[fn], acc[fm][fn], 0, 0, 0);
    __syncthreads();
  }
#pragma unroll
  for (int fm = 0; fm < 4; ++fm)
#pragma unroll
    for (int fn = 0; fn < 2; ++fn) {
      int mg0 = m0 + wm * 64 + fm * 16 + ks * 4;
      int ng = n0 + wn * 32 + fn * 16 + fr;
      float bv = bias[ng];
      int ngs = PERM ? ((ng & 255) * 4 + (ng >> 8)) : ng;
#pragma unroll
      for (int r = 0; r < 4; ++r) {
        float v = acc[fm][fn][r] + bv;
        if constexpr (RELU) v = fmaxf(v, 0.f);
        C[(size_t)(mg0 + r) * N + ngs] = __float2half(v);
      }
    }
}

// ---------------- recurrence: MX fp8 K=128 MFMA GEMV, one block/batch --------
// R13 structure (best measured: 510us). 512 threads = 8 waves = 2/SIMD;
// budget 256 regs/thread; weights 128 regs, all resident; one raw barrier.
// R15 fix: per-step VMEM ISSUE ORDER is load-then-store. With store-first,
// the compiler's wait for zx_n (newest VMEM op) is vmcnt(0), which drains
// the pp store's HBM write-ack (~300-600cy) into every step. Load-first
// makes the zx wait vmcnt(1) and leaves the store in flight.
__attribute__((amdgpu_waves_per_eu(2, 2)))
__global__ void __launch_bounds__(512, 1)
lstm_rec(const uint8_t* __restrict__ whP,   // [1024][256] fp8 (x16)
         const __half* __restrict__ zxi,    // [B*T][256u][4gate] f16
         const float* __restrict__ maskF,   // [B*T]
         const float* __restrict__ Wp,      // [256]
         __half* __restrict__ ppG)          // [B*T][256] f16: h*wp per col
{
  __shared__ __align__(16) uint8_t hpk[2][256];      // fp8 h (ping-pong)
  __shared__ float mlds[TT];                         // 2KB mask row

  const int b = blockIdx.x;
  const int t = threadIdx.x;
  const int lane = t & 63, w = t >> 6;       // 8 waves
  const int fr = lane & 15, q = lane >> 4;   // q = k-slice group
  const int jj = q & 1;                      // cell-phase col-half select
  const int SC1 = 0x7F7F7F7F;                // E8M0 x1.0 scales

  const uint4* whP4 = (const uint4*)whP;  // uint4 idx = col*16 + kt*8 + q*2

  // --- preload ALL weight B-frags: kt 0..1, tile T = g*2+j (8 tiles) ---
  // col(T) = g*256 + w*32 + j*16 + fr;  128 regs/thread total.
  pk32 bfr[2][8];
#pragma unroll
  for (int kt = 0; kt < 2; ++kt)
#pragma unroll
    for (int g = 0; g < 4; ++g)
#pragma unroll
      for (int j = 0; j < 2; ++j) {
        int col = g * 256 + w * 32 + j * 16 + fr;
        bfr[kt][g * 2 + j].u4[0] = whP4[col * 16 + kt * 8 + q * 2];
        bfr[kt][g * 2 + j].u4[1] = whP4[col * 16 + kt * 8 + q * 2 + 1];
      }
#pragma unroll
  for (int kt = 0; kt < 2; ++kt)
#pragma unroll
    for (int T = 0; T < 8; ++T) {
      asm volatile("" : "+v"(bfr[kt][T].u4[0].x), "+v"(bfr[kt][T].u4[0].y),
                        "+v"(bfr[kt][T].u4[0].z), "+v"(bfr[kt][T].u4[0].w));
      asm volatile("" : "+v"(bfr[kt][T].u4[1].x), "+v"(bfr[kt][T].u4[1].y),
                        "+v"(bfr[kt][T].u4[1].z), "+v"(bfr[kt][T].u4[1].w));
    }

  if (t < 64) ((uint32_t*)hpk[0])[t] = 0u;
  mlds[t] = maskF[b * TT + t];               // 512 threads = TT exactly
  float c_state = 0.f, h_state = 0.f;
  // this thread's cell column (lanes 32-63 mirror 0-31)
  const int ue = w * 32 + jj * 16 + fr;
  float wpv = Wp[ue];
  __syncthreads();

  const uint2* zp = (const uint2*)(zxi + (size_t)b * TT * GG);  // 256 uint2/row
  __half* ppp = ppG + (size_t)b * TT * UU;

  // --- software pipeline: preload step 0's zx (one b64: i,f,g,o packed) ---
  uint2 zx_c = zp[ue];
  __half pp_prev = __float2half(0.f);

  int p = 0;
  for (int step = 0; step < TT; ++step) {
    // LOAD FIRST: next step's zx; consumed next iteration (vmcnt(1) wait)
    const uint2* zq = zp + ((step + 1 < TT) ? 256 : 0);
    uint2 zx_n = zq[ue];
    // STORE SECOND: previous step's pp stays in flight past the zx wait
    if (step > 0 && lane < 32) ppp[(size_t)(step - 1) * UU + w * 32 + lane] = pp_prev;
    float mval = mlds[step];

    // ---- MFMA phase: 8 tiles x 2 K-halves, all-register B ----
    const uint4* hp4 = (const uint4*)hpk[p];
    pk32 a0, a1;
    a0.u4[0] = hp4[q * 2];     a0.u4[1] = hp4[q * 2 + 1];
    a1.u4[0] = hp4[8 + q * 2]; a1.u4[1] = hp4[8 + q * 2 + 1];
    f32x4 d[8];
#pragma unroll
    for (int T = 0; T < 8; ++T) {
      f32x4 z = {0.f, 0.f, 0.f, 0.f};
      z = __builtin_amdgcn_mfma_scale_f32_16x16x128_f8f6f4(
          a0.v, bfr[0][T].v, z, 0, 0, 0, SC1, 0, SC1);
      d[T] = __builtin_amdgcn_mfma_scale_f32_16x16x128_f8f6f4(
          a1.v, bfr[1][T].v, z, 0, 0, 0, SC1, 0, SC1);
    }
    // extract reg0 (D rows replicated) into named scalars; pick half via jj
    float s0 = d[0][0], s1 = d[1][0], s2 = d[2][0], s3 = d[3][0];
    float s4 = d[4][0], s5 = d[5][0], s6 = d[6][0], s7 = d[7][0];

    // ---- cell phase (lanes 32-63 mirror; writes guarded) ----
    {
      union { uint2 u2; __half2 h2[2]; } zz;
      zz.u2 = zx_c;
      float2 zif = __half22float2(zz.h2[0]);  // (i, f)
      float2 zgo = __half22float2(zz.h2[1]);  // (g, o)
      float gi = fmaf(jj ? s1 : s0, 0.0625f, zif.x);
      float gf = fmaf(jj ? s3 : s2, 0.0625f, zif.y);
      float gg = fmaf(jj ? s5 : s4, 0.0625f, zgo.x);
      float go = fmaf(jj ? s7 : s6, 0.0625f, zgo.y);
      float ig = sigmf_(gi);
      float fg = sigmf_(gf);
      float g_ = tanhf_(gg);
      float og = sigmf_(go);
      float cn = fg * c_state + ig * g_;
      float hn = og * tanhf_(cn);
      bool on = (mval > 0.5f);
      c_state = on ? cn : c_state;
      h_state = on ? hn : h_state;
      __hip_fp8_e4m3 f8(h_state);
      if (lane < 32) hpk[p ^ 1][w * 32 + lane] = (uint8_t)f8.__x;
      pp_prev = __float2half(h_state * wpv);
    }
    // raw barrier: order LDS (h ping-pong); VMEM stays in flight.
    asm volatile("s_waitcnt lgkmcnt(0)" ::: "memory");
    __builtin_amdgcn_s_barrier();
    asm volatile("" ::: "memory");
    p ^= 1;
    zp += 256;
    zx_c = zx_n;
  }
  if (lane < 32) ppp[(size_t)(TT - 1) * UU + w * 32 + lane] = pp_prev;
}

// --------- projection: out[row] = sigmoid(sum_u ppG[row][u] + bp) ------------
__global__ __launch_bounds__(256) void proj_kernel(const __half* __restrict__ ppG,
                                                   const float* __restrict__ bp,
                                                   float* __restrict__ out) {
  int row = blockIdx.x * 4 + (threadIdx.x >> 6);
  int lane = threadIdx.x & 63;
  const ushort4* pr = (const ushort4*)(ppG + (size_t)row * UU);
  ushort4 v = pr[lane];
  __half2 a = *reinterpret_cast<__half2*>(&v.x);
  __half2 c = *reinterpret_cast<__half2*>(&v.z);
  float2 af = __half22float2(a), cf = __half22float2(c);
  float s = af.x + af.y + cf.x + cf.y;
#pragma unroll
  for (int off = 32; off > 0; off >>= 1) s += __shfl_down(s, off);
  if (lane == 0) out[row] = 1.f / (1.f + __expf(-(s + bp[0])));
}

extern "C" void kernel_launch(void* const* d_in, const int* in_sizes, int n_in,
                              void* d_out, int out_size, void* d_ws, size_t ws_size,
                              hipStream_t stream) {
  const float* x = (const float*)d_in[0];
  const float* Wfc = (const float*)d_in[1];
  const float* bfc = (const float*)d_in[2];
  const float* Wx = (const float*)d_in[3];
  const float* Wh = (const float*)d_in[4];
  const float* blstm = (const float*)d_in[5];
  const float* Wp = (const float*)d_in[6];
  const float* bp = (const float*)d_in[7];
  float* out = (float*)d_out;

  char* ws = (char*)d_ws;
  float* maskF = (float*)(ws);                                   // 128 KB
  __half* zh = (__half*)(ws + 131072);                           // 16.78 MB
  __half* zxi = (__half*)(ws + 131072 + 16777216);               // 67.1 MB
  uint8_t* whP = (uint8_t*)(ws + 131072 + 16777216 + 67108864);  // 256 KB
  __half* ppG = zh;  // zh is dead after gemm_zx; exact size match (16.78 MB)

  mask_kernel<<<BB * TT, 256, 0, stream>>>(x, maskF);
  pack_whP<<<GG, 256, 0, stream>>>(Wh, whP);
  gemm16<float, true, false><<<dim3((BB * TT) / 128, UU / 64), 256, 0, stream>>>(
      x, Wfc, bfc, zh, BB * TT, UU, FF);
  gemm16<__half, false, true><<<dim3((BB * TT) / 128, GG / 64), 256, 0, stream>>>(
      zh, Wx, blstm, zxi, BB * TT, GG, UU);
  lstm_rec<<<BB, 512, 0, stream>>>(whP, zxi, maskF, Wp, ppG);
  proj_kernel<<<(BB * TT) / 4, 256, 0, stream>>>(ppG, bp, out);
}

// Round 16
// 649.768 us; speedup vs baseline: 1.2432x; 1.0254x over previous
//
#include <hip/hip_runtime.h>
#include <hip/hip_fp16.h>
#include <hip/hip_fp8.h>
#include <cstdint>

// B=64, T=512, F=1024, U=256, G=4U=1024
#define BB 64
#define TT 512
#define FF 1024
#define UU 256
#define GG 1024

typedef _Float16 f16x8 __attribute__((ext_vector_type(8)));
typedef float f32x4 __attribute__((ext_vector_type(4)));
typedef int i32x8 __attribute__((ext_vector_type(8)));

typedef union { uint4 u4[2]; i32x8 v; } pk32;  // 32 fp8 = one K=128 MFMA operand

__device__ __forceinline__ float sigmf_(float x) { return 1.f / (1.f + __expf(-x)); }
__device__ __forceinline__ float tanhf_(float x) { return 1.f - 2.f / (1.f + __expf(2.f * x)); }

// ---------------- mask kernel: mask[b,t] = any(x[b,t,:] != 0) ----------------
__global__ __launch_bounds__(256) void mask_kernel(const float* __restrict__ x,
                                                   float* __restrict__ maskF) {
  int row = blockIdx.x;
  int tid = threadIdx.x;
  const float4* xr = (const float4*)(x + (size_t)row * FF);
  float4 v = xr[tid];
  bool nz = (v.x != 0.f) || (v.y != 0.f) || (v.z != 0.f) || (v.w != 0.f);
  __shared__ int flag;
  if (tid == 0) flag = 0;
  __syncthreads();
  if (__any(nz)) {
    if ((tid & 63) == 0) atomicOr(&flag, 1);
  }
  __syncthreads();
  if (tid == 0) maskF[row] = flag ? 1.f : 0.f;
}

// ---- pack W_h (256x1024 f32, [u][c]) -> whP [1024 cols][256 k] fp8 e4m3 -----
__global__ __launch_bounds__(256) void pack_whP(const float* __restrict__ Wh,
                                                uint8_t* __restrict__ whP) {
  int col = blockIdx.x;   // 0..1023
  int k = threadIdx.x;    // 0..255
  __hip_fp8_e4m3 f(Wh[(size_t)k * GG + col] * 16.f);
  whP[col * 256 + k] = (uint8_t)f.__x;
}

// ------------- MFMA GEMM, 128x128 tile: C(f16) = [relu](A @ B + bias) --------
// A: M x K (row-major, TA = float or __half), B: K x N (row-major f32).
// 256 threads = 4 waves (2x2); wave-tile 64x64 = 4x4 frags = 16 MFMAs/K-tile.
// Wider N-tile (64->128) halves A re-reads across N column-blocks (the R15
// aux-cost analysis: gemm_fc re-read x 4x from HBM, gemm_zx re-read zh 16x).
// PERM: store column ng at permuted position (ng&255)*4 + (ng>>8).
template <typename TA, bool RELU, bool PERM>
__global__ __launch_bounds__(256) void gemm_big(const TA* __restrict__ A,
                                                const float* __restrict__ Bm,
                                                const float* __restrict__ bias,
                                                __half* __restrict__ C,
                                                int M, int N, int K) {
  __shared__ _Float16 As[128][40];  // padded stride 80B
  __shared__ _Float16 Bs[128][40];  // transposed: Bs[n][k]
  int tid = threadIdx.x;
  int lane = tid & 63, w = tid >> 6;
  int wm = w & 1, wn = w >> 1;
  int m0 = blockIdx.x * 128, n0 = blockIdx.y * 128;
  int fr = lane & 15, ks = lane >> 4;

  f32x4 acc[4][4];
#pragma unroll
  for (int i = 0; i < 4; ++i)
#pragma unroll
    for (int j = 0; j < 4; ++j) acc[i][j] = (f32x4){0.f, 0.f, 0.f, 0.f};

  for (int k0 = 0; k0 < K; k0 += 32) {
    {
      int r = tid >> 3, kq = (tid & 7) * 4;
#pragma unroll
      for (int i = 0; i < 4; ++i) {
        int row = r + 32 * i;
        const TA* src = A + (size_t)(m0 + row) * K + k0 + kq;
        if constexpr (sizeof(TA) == 4) {
          float4 v = *reinterpret_cast<const float4*>(src);
          union { uint2 u; _Float16 h[4]; } pk;
          pk.h[0] = (_Float16)v.x; pk.h[1] = (_Float16)v.y;
          pk.h[2] = (_Float16)v.z; pk.h[3] = (_Float16)v.w;
          *reinterpret_cast<uint2*>(&As[row][kq]) = pk.u;
        } else {
          uint2 v = *reinterpret_cast<const uint2*>(src);
          *reinterpret_cast<uint2*>(&As[row][kq]) = v;
        }
      }
      // stage B transposed: 32 k x 128 n
      int nn = tid & 127, kb = tid >> 7;  // kb in {0,1}
#pragma unroll
      for (int i = 0; i < 16; ++i) {
        int kk = kb + 2 * i;
        Bs[nn][kk] = (_Float16)Bm[(size_t)(k0 + kk) * N + n0 + nn];
      }
    }
    __syncthreads();
    f16x8 af[4], bf[4];
#pragma unroll
    for (int fm = 0; fm < 4; ++fm)
      af[fm] = *reinterpret_cast<const f16x8*>(&As[wm * 64 + fm * 16 + fr][ks * 8]);
#pragma unroll
    for (int fn = 0; fn < 4; ++fn)
      bf[fn] = *reinterpret_cast<const f16x8*>(&Bs[wn * 64 + fn * 16 + fr][ks * 8]);
#pragma unroll
    for (int fm = 0; fm < 4; ++fm)
#pragma unroll
      for (int fn = 0; fn < 4; ++fn)
        acc[fm][fn] = __builtin_amdgcn_mfma_f32_16x16x32_f16(af[fm], bf[fn], acc[fm][fn], 0, 0, 0);
    __syncthreads();
  }
  // epilogue: C/D layout col=lane&15, row=(lane>>4)*4+r  (m89-verified)
#pragma unroll
  for (int fm = 0; fm < 4; ++fm)
#pragma unroll
    for (int fn = 0; fn < 4; ++fn) {
      int mg0 = m0 + wm * 64 + fm * 16 + ks * 4;
      int ng = n0 + wn * 64 + fn * 16 + fr;
      float bv = bias[ng];
      int ngs = PERM ? ((ng & 255) * 4 + (ng >> 8)) : ng;
#pragma unroll
      for (int r = 0; r < 4; ++r) {
        float v = acc[fm][fn][r] + bv;
        if constexpr (RELU) v = fmaxf(v, 0.f);
        C[(size_t)(mg0 + r) * N + ngs] = __float2half(v);
      }
    }
}

// ---------------- recurrence: MX fp8 K=128 MFMA GEMV, one block/batch --------
// CHAMPION (R13/R15, 507us) - unchanged. 512 threads = 8 waves = 2/SIMD;
// budget 256 regs/thread; W_h fp8 all-register (128 regs); one raw barrier
// per step (lgkmcnt-only); zx gate-interleaved b64 load, pipelined 1 ahead;
// pp export deferred, load-before-store issue order.
__attribute__((amdgpu_waves_per_eu(2, 2)))
__global__ void __launch_bounds__(512, 1)
lstm_rec(const uint8_t* __restrict__ whP,   // [1024][256] fp8 (x16)
         const __half* __restrict__ zxi,    // [B*T][256u][4gate] f16
         const float* __restrict__ maskF,   // [B*T]
         const float* __restrict__ Wp,      // [256]
         __half* __restrict__ ppG)          // [B*T][256] f16: h*wp per col
{
  __shared__ __align__(16) uint8_t hpk[2][256];      // fp8 h (ping-pong)
  __shared__ float mlds[TT];                         // 2KB mask row

  const int b = blockIdx.x;
  const int t = threadIdx.x;
  const int lane = t & 63, w = t >> 6;       // 8 waves
  const int fr = lane & 15, q = lane >> 4;   // q = k-slice group
  const int jj = q & 1;                      // cell-phase col-half select
  const int SC1 = 0x7F7F7F7F;                // E8M0 x1.0 scales

  const uint4* whP4 = (const uint4*)whP;  // uint4 idx = col*16 + kt*8 + q*2

  // --- preload ALL weight B-frags: kt 0..1, tile T = g*2+j (8 tiles) ---
  pk32 bfr[2][8];
#pragma unroll
  for (int kt = 0; kt < 2; ++kt)
#pragma unroll
    for (int g = 0; g < 4; ++g)
#pragma unroll
      for (int j = 0; j < 2; ++j) {
        int col = g * 256 + w * 32 + j * 16 + fr;
        bfr[kt][g * 2 + j].u4[0] = whP4[col * 16 + kt * 8 + q * 2];
        bfr[kt][g * 2 + j].u4[1] = whP4[col * 16 + kt * 8 + q * 2 + 1];
      }
#pragma unroll
  for (int kt = 0; kt < 2; ++kt)
#pragma unroll
    for (int T = 0; T < 8; ++T) {
      asm volatile("" : "+v"(bfr[kt][T].u4[0].x), "+v"(bfr[kt][T].u4[0].y),
                        "+v"(bfr[kt][T].u4[0].z), "+v"(bfr[kt][T].u4[0].w));
      asm volatile("" : "+v"(bfr[kt][T].u4[1].x), "+v"(bfr[kt][T].u4[1].y),
                        "+v"(bfr[kt][T].u4[1].z), "+v"(bfr[kt][T].u4[1].w));
    }

  if (t < 64) ((uint32_t*)hpk[0])[t] = 0u;
  mlds[t] = maskF[b * TT + t];               // 512 threads = TT exactly
  float c_state = 0.f, h_state = 0.f;
  const int ue = w * 32 + jj * 16 + fr;      // this thread's cell column
  float wpv = Wp[ue];
  __syncthreads();

  const uint2* zp = (const uint2*)(zxi + (size_t)b * TT * GG);  // 256 uint2/row
  __half* ppp = ppG + (size_t)b * TT * UU;

  uint2 zx_c = zp[ue];
  __half pp_prev = __float2half(0.f);

  int p = 0;
  for (int step = 0; step < TT; ++step) {
    // LOAD FIRST: next step's zx (vmcnt(1) wait); store stays in flight
    const uint2* zq = zp + ((step + 1 < TT) ? 256 : 0);
    uint2 zx_n = zq[ue];
    if (step > 0 && lane < 32) ppp[(size_t)(step - 1) * UU + w * 32 + lane] = pp_prev;
    float mval = mlds[step];

    // ---- MFMA phase: 8 tiles x 2 K-halves, all-register B ----
    const uint4* hp4 = (const uint4*)hpk[p];
    pk32 a0, a1;
    a0.u4[0] = hp4[q * 2];     a0.u4[1] = hp4[q * 2 + 1];
    a1.u4[0] = hp4[8 + q * 2]; a1.u4[1] = hp4[8 + q * 2 + 1];
    f32x4 d[8];
#pragma unroll
    for (int T = 0; T < 8; ++T) {
      f32x4 z = {0.f, 0.f, 0.f, 0.f};
      z = __builtin_amdgcn_mfma_scale_f32_16x16x128_f8f6f4(
          a0.v, bfr[0][T].v, z, 0, 0, 0, SC1, 0, SC1);
      d[T] = __builtin_amdgcn_mfma_scale_f32_16x16x128_f8f6f4(
          a1.v, bfr[1][T].v, z, 0, 0, 0, SC1, 0, SC1);
    }
    float s0 = d[0][0], s1 = d[1][0], s2 = d[2][0], s3 = d[3][0];
    float s4 = d[4][0], s5 = d[5][0], s6 = d[6][0], s7 = d[7][0];

    // ---- cell phase (lanes 32-63 mirror; writes guarded) ----
    {
      union { uint2 u2; __half2 h2[2]; } zz;
      zz.u2 = zx_c;
      float2 zif = __half22float2(zz.h2[0]);  // (i, f)
      float2 zgo = __half22float2(zz.h2[1]);  // (g, o)
      float gi = fmaf(jj ? s1 : s0, 0.0625f, zif.x);
      float gf = fmaf(jj ? s3 : s2, 0.0625f, zif.y);
      float gg = fmaf(jj ? s5 : s4, 0.0625f, zgo.x);
      float go = fmaf(jj ? s7 : s6, 0.0625f, zgo.y);
      float ig = sigmf_(gi);
      float fg = sigmf_(gf);
      float g_ = tanhf_(gg);
      float og = sigmf_(go);
      float cn = fg * c_state + ig * g_;
      float hn = og * tanhf_(cn);
      bool on = (mval > 0.5f);
      c_state = on ? cn : c_state;
      h_state = on ? hn : h_state;
      __hip_fp8_e4m3 f8(h_state);
      if (lane < 32) hpk[p ^ 1][w * 32 + lane] = (uint8_t)f8.__x;
      pp_prev = __float2half(h_state * wpv);
    }
    // raw barrier: order LDS (h ping-pong); VMEM stays in flight.
    asm volatile("s_waitcnt lgkmcnt(0)" ::: "memory");
    __builtin_amdgcn_s_barrier();
    asm volatile("" ::: "memory");
    p ^= 1;
    zp += 256;
    zx_c = zx_n;
  }
  if (lane < 32) ppp[(size_t)(TT - 1) * UU + w * 32 + lane] = pp_prev;
}

// --------- projection: out[row] = sigmoid(sum_u ppG[row][u] + bp) ------------
__global__ __launch_bounds__(256) void proj_kernel(const __half* __restrict__ ppG,
                                                   const float* __restrict__ bp,
                                                   float* __restrict__ out) {
  int row = blockIdx.x * 4 + (threadIdx.x >> 6);
  int lane = threadIdx.x & 63;
  const ushort4* pr = (const ushort4*)(ppG + (size_t)row * UU);
  ushort4 v = pr[lane];
  __half2 a = *reinterpret_cast<__half2*>(&v.x);
  __half2 c = *reinterpret_cast<__half2*>(&v.z);
  float2 af = __half22float2(a), cf = __half22float2(c);
  float s = af.x + af.y + cf.x + cf.y;
#pragma unroll
  for (int off = 32; off > 0; off >>= 1) s += __shfl_down(s, off);
  if (lane == 0) out[row] = 1.f / (1.f + __expf(-(s + bp[0])));
}

extern "C" void kernel_launch(void* const* d_in, const int* in_sizes, int n_in,
                              void* d_out, int out_size, void* d_ws, size_t ws_size,
                              hipStream_t stream) {
  const float* x = (const float*)d_in[0];
  const float* Wfc = (const float*)d_in[1];
  const float* bfc = (const float*)d_in[2];
  const float* Wx = (const float*)d_in[3];
  const float* Wh = (const float*)d_in[4];
  const float* blstm = (const float*)d_in[5];
  const float* Wp = (const float*)d_in[6];
  const float* bp = (const float*)d_in[7];
  float* out = (float*)d_out;

  char* ws = (char*)d_ws;
  float* maskF = (float*)(ws);                                   // 128 KB
  __half* zh = (__half*)(ws + 131072);                           // 16.78 MB
  __half* zxi = (__half*)(ws + 131072 + 16777216);               // 67.1 MB
  uint8_t* whP = (uint8_t*)(ws + 131072 + 16777216 + 67108864);  // 256 KB
  __half* ppG = zh;  // zh is dead after gemm_zx; exact size match (16.78 MB)

  mask_kernel<<<BB * TT, 256, 0, stream>>>(x, maskF);
  pack_whP<<<GG, 256, 0, stream>>>(Wh, whP);
  gemm_big<float, true, false><<<dim3((BB * TT) / 128, UU / 128), 256, 0, stream>>>(
      x, Wfc, bfc, zh, BB * TT, UU, FF);
  gemm_big<__half, false, true><<<dim3((BB * TT) / 128, GG / 128), 256, 0, stream>>>(
      zh, Wx, blstm, zxi, BB * TT, GG, UU);
  lstm_rec<<<BB, 512, 0, stream>>>(whP, zxi, maskF, Wp, ppG);
  proj_kernel<<<(BB * TT) / 4, 256, 0, stream>>>(ppG, bp, out);
}

// Round 18
// 630.357 us; speedup vs baseline: 1.2814x; 1.0308x over previous
//
#include <hip/hip_runtime.h>
#include <hip/hip_fp16.h>
#include <hip/hip_fp8.h>
#include <cstdint>

// B=64, T=512, F=1024, U=256, G=4U=1024
#define BB 64
#define TT 512
#define FF 1024
#define UU 256
#define GG 1024

typedef _Float16 f16x8 __attribute__((ext_vector_type(8)));
typedef float f32x4 __attribute__((ext_vector_type(4)));
typedef int i32x8 __attribute__((ext_vector_type(8)));

typedef union { uint4 u4[2]; i32x8 v; } pk32;  // 32 fp8 = one K=128 MFMA operand

__device__ __forceinline__ float sigmf_(float x) { return 1.f / (1.f + __expf(-x)); }
__device__ __forceinline__ float tanhf_(float x) { return 1.f - 2.f / (1.f + __expf(2.f * x)); }

// ---- pack W_h (256x1024 f32, [u][c]) -> whP [1024 cols][256 k] fp8 e4m3 -----
__global__ __launch_bounds__(256) void pack_whP(const float* __restrict__ Wh,
                                                uint8_t* __restrict__ whP) {
  int col = blockIdx.x;   // 0..1023
  int k = threadIdx.x;    // 0..255
  __hip_fp8_e4m3 f(Wh[(size_t)k * GG + col] * 16.f);
  whP[col * 256 + k] = (uint8_t)f.__x;
}

// ------------- MFMA GEMM, 128x128 tile: C(f16) = [relu](A @ B + bias) --------
// R16-proven shape. 256 threads = 4 waves (2x2); wave-tile 64x64.
// DOMASK (fc only): while staging A (which reads ALL of x anyway), OR-reduce
// per-row nonzero-ness -> maskF. Replaces the separate mask_kernel and its
// full 134MB re-read of x. Predicate identical to reference (x pre-zeroed
// outside valid rows). blockIdx.y==0 writes (duplicate-safe anyway).
// PERM: store column ng at permuted position (ng&255)*4 + (ng>>8).
template <typename TA, bool RELU, bool PERM, bool DOMASK>
__global__ __launch_bounds__(256) void gemm_big(const TA* __restrict__ A,
                                                const float* __restrict__ Bm,
                                                const float* __restrict__ bias,
                                                __half* __restrict__ C,
                                                float* __restrict__ maskF,
                                                int M, int N, int K) {
  __shared__ _Float16 As[128][40];  // padded stride 80B
  __shared__ _Float16 Bs[128][40];  // transposed: Bs[n][k]
  __shared__ int rowflag[128];
  int tid = threadIdx.x;
  int lane = tid & 63, w = tid >> 6;
  int wm = w & 1, wn = w >> 1;
  int m0 = blockIdx.x * 128, n0 = blockIdx.y * 128;
  int fr = lane & 15, ks = lane >> 4;

  if (DOMASK && tid < 128) rowflag[tid] = 0;
  bool nz0 = false, nz1 = false, nz2 = false, nz3 = false;

  f32x4 acc[4][4];
#pragma unroll
  for (int i = 0; i < 4; ++i)
#pragma unroll
    for (int j = 0; j < 4; ++j) acc[i][j] = (f32x4){0.f, 0.f, 0.f, 0.f};

  for (int k0 = 0; k0 < K; k0 += 32) {
    {
      int r = tid >> 3, kq = (tid & 7) * 4;
#pragma unroll
      for (int i = 0; i < 4; ++i) {
        int row = r + 32 * i;
        const TA* src = A + (size_t)(m0 + row) * K + k0 + kq;
        if constexpr (sizeof(TA) == 4) {
          float4 v = *reinterpret_cast<const float4*>(src);
          if constexpr (DOMASK) {
            bool nz = (v.x != 0.f) || (v.y != 0.f) || (v.z != 0.f) || (v.w != 0.f);
            if (i == 0) nz0 |= nz;
            if (i == 1) nz1 |= nz;
            if (i == 2) nz2 |= nz;
            if (i == 3) nz3 |= nz;
          }
          union { uint2 u; _Float16 h[4]; } pk;
          pk.h[0] = (_Float16)v.x; pk.h[1] = (_Float16)v.y;
          pk.h[2] = (_Float16)v.z; pk.h[3] = (_Float16)v.w;
          *reinterpret_cast<uint2*>(&As[row][kq]) = pk.u;
        } else {
          uint2 v = *reinterpret_cast<const uint2*>(src);
          *reinterpret_cast<uint2*>(&As[row][kq]) = v;
        }
      }
      // stage B transposed: 32 k x 128 n
      int nn = tid & 127, kb = tid >> 7;  // kb in {0,1}
#pragma unroll
      for (int i = 0; i < 16; ++i) {
        int kk = kb + 2 * i;
        Bs[nn][kk] = (_Float16)Bm[(size_t)(k0 + kk) * N + n0 + nn];
      }
    }
    __syncthreads();
    f16x8 af[4], bf[4];
#pragma unroll
    for (int fm = 0; fm < 4; ++fm)
      af[fm] = *reinterpret_cast<const f16x8*>(&As[wm * 64 + fm * 16 + fr][ks * 8]);
#pragma unroll
    for (int fn = 0; fn < 4; ++fn)
      bf[fn] = *reinterpret_cast<const f16x8*>(&Bs[wn * 64 + fn * 16 + fr][ks * 8]);
#pragma unroll
    for (int fm = 0; fm < 4; ++fm)
#pragma unroll
      for (int fn = 0; fn < 4; ++fn)
        acc[fm][fn] = __builtin_amdgcn_mfma_f32_16x16x32_f16(af[fm], bf[fn], acc[fm][fn], 0, 0, 0);
    __syncthreads();
  }
  // epilogue: C/D layout col=lane&15, row=(lane>>4)*4+r  (m89-verified)
#pragma unroll
  for (int fm = 0; fm < 4; ++fm)
#pragma unroll
    for (int fn = 0; fn < 4; ++fn) {
      int mg0 = m0 + wm * 64 + fm * 16 + ks * 4;
      int ng = n0 + wn * 64 + fn * 16 + fr;
      float bv = bias[ng];
      int ngs = PERM ? ((ng & 255) * 4 + (ng >> 8)) : ng;
#pragma unroll
      for (int r = 0; r < 4; ++r) {
        float v = acc[fm][fn][r] + bv;
        if constexpr (RELU) v = fmaxf(v, 0.f);
        C[(size_t)(mg0 + r) * N + ngs] = __float2half(v);
      }
    }
  if constexpr (DOMASK) {
    int r = tid >> 3;
    if (nz0) atomicOr(&rowflag[r], 1);
    if (nz1) atomicOr(&rowflag[r + 32], 1);
    if (nz2) atomicOr(&rowflag[r + 64], 1);
    if (nz3) atomicOr(&rowflag[r + 96], 1);
    __syncthreads();
    if (tid < 128 && blockIdx.y == 0) maskF[m0 + tid] = rowflag[tid] ? 1.f : 0.f;
  }
}

// ---------------- recurrence: MX fp8 K=128 MFMA GEMV, one block/batch --------
// CHAMPION (R13/R15/R16, ~505us, counters byte-stable) - unchanged, final.
// 512 threads = 8 waves = 2/SIMD; budget 256 regs/thread; W_h fp8
// all-register (128 regs); one raw barrier per step (lgkmcnt-only);
// zx gate-interleaved b64 load pipelined 1 ahead; pp export deferred,
// load-before-store issue order.
__attribute__((amdgpu_waves_per_eu(2, 2)))
__global__ void __launch_bounds__(512, 1)
lstm_rec(const uint8_t* __restrict__ whP,   // [1024][256] fp8 (x16)
         const __half* __restrict__ zxi,    // [B*T][256u][4gate] f16
         const float* __restrict__ maskF,   // [B*T]
         const float* __restrict__ Wp,      // [256]
         __half* __restrict__ ppG)          // [B*T][256] f16: h*wp per col
{
  __shared__ __align__(16) uint8_t hpk[2][256];      // fp8 h (ping-pong)
  __shared__ float mlds[TT];                         // 2KB mask row

  const int b = blockIdx.x;
  const int t = threadIdx.x;
  const int lane = t & 63, w = t >> 6;       // 8 waves
  const int fr = lane & 15, q = lane >> 4;   // q = k-slice group
  const int jj = q & 1;                      // cell-phase col-half select
  const int SC1 = 0x7F7F7F7F;                // E8M0 x1.0 scales

  const uint4* whP4 = (const uint4*)whP;  // uint4 idx = col*16 + kt*8 + q*2

  // --- preload ALL weight B-frags: kt 0..1, tile T = g*2+j (8 tiles) ---
  pk32 bfr[2][8];
#pragma unroll
  for (int kt = 0; kt < 2; ++kt)
#pragma unroll
    for (int g = 0; g < 4; ++g)
#pragma unroll
      for (int j = 0; j < 2; ++j) {
        int col = g * 256 + w * 32 + j * 16 + fr;
        bfr[kt][g * 2 + j].u4[0] = whP4[col * 16 + kt * 8 + q * 2];
        bfr[kt][g * 2 + j].u4[1] = whP4[col * 16 + kt * 8 + q * 2 + 1];
      }
#pragma unroll
  for (int kt = 0; kt < 2; ++kt)
#pragma unroll
    for (int T = 0; T < 8; ++T) {
      asm volatile("" : "+v"(bfr[kt][T].u4[0].x), "+v"(bfr[kt][T].u4[0].y),
                        "+v"(bfr[kt][T].u4[0].z), "+v"(bfr[kt][T].u4[0].w));
      asm volatile("" : "+v"(bfr[kt][T].u4[1].x), "+v"(bfr[kt][T].u4[1].y),
                        "+v"(bfr[kt][T].u4[1].z), "+v"(bfr[kt][T].u4[1].w));
    }

  if (t < 64) ((uint32_t*)hpk[0])[t] = 0u;
  mlds[t] = maskF[b * TT + t];               // 512 threads = TT exactly
  float c_state = 0.f, h_state = 0.f;
  const int ue = w * 32 + jj * 16 + fr;      // this thread's cell column
  float wpv = Wp[ue];
  __syncthreads();

  const uint2* zp = (const uint2*)(zxi + (size_t)b * TT * GG);  // 256 uint2/row
  __half* ppp = ppG + (size_t)b * TT * UU;

  uint2 zx_c = zp[ue];
  __half pp_prev = __float2half(0.f);

  int p = 0;
  for (int step = 0; step < TT; ++step) {
    // LOAD FIRST: next step's zx (vmcnt(1) wait); store stays in flight
    const uint2* zq = zp + ((step + 1 < TT) ? 256 : 0);
    uint2 zx_n = zq[ue];
    if (step > 0 && lane < 32) ppp[(size_t)(step - 1) * UU + w * 32 + lane] = pp_prev;
    float mval = mlds[step];

    // ---- MFMA phase: 8 tiles x 2 K-halves, all-register B ----
    const uint4* hp4 = (const uint4*)hpk[p];
    pk32 a0, a1;
    a0.u4[0] = hp4[q * 2];     a0.u4[1] = hp4[q * 2 + 1];
    a1.u4[0] = hp4[8 + q * 2]; a1.u4[1] = hp4[8 + q * 2 + 1];
    f32x4 d[8];
#pragma unroll
    for (int T = 0; T < 8; ++T) {
      f32x4 z = {0.f, 0.f, 0.f, 0.f};
      z = __builtin_amdgcn_mfma_scale_f32_16x16x128_f8f6f4(
          a0.v, bfr[0][T].v, z, 0, 0, 0, SC1, 0, SC1);
      d[T] = __builtin_amdgcn_mfma_scale_f32_16x16x128_f8f6f4(
          a1.v, bfr[1][T].v, z, 0, 0, 0, SC1, 0, SC1);
    }
    float s0 = d[0][0], s1 = d[1][0], s2 = d[2][0], s3 = d[3][0];
    float s4 = d[4][0], s5 = d[5][0], s6 = d[6][0], s7 = d[7][0];

    // ---- cell phase (lanes 32-63 mirror; writes guarded) ----
    {
      union { uint2 u2; __half2 h2[2]; } zz;
      zz.u2 = zx_c;
      float2 zif = __half22float2(zz.h2[0]);  // (i, f)
      float2 zgo = __half22float2(zz.h2[1]);  // (g, o)
      float gi = fmaf(jj ? s1 : s0, 0.0625f, zif.x);
      float gf = fmaf(jj ? s3 : s2, 0.0625f, zif.y);
      float gg = fmaf(jj ? s5 : s4, 0.0625f, zgo.x);
      float go = fmaf(jj ? s7 : s6, 0.0625f, zgo.y);
      float ig = sigmf_(gi);
      float fg = sigmf_(gf);
      float g_ = tanhf_(gg);
      float og = sigmf_(go);
      float cn = fg * c_state + ig * g_;
      float hn = og * tanhf_(cn);
      bool on = (mval > 0.5f);
      c_state = on ? cn : c_state;
      h_state = on ? hn : h_state;
      __hip_fp8_e4m3 f8(h_state);
      if (lane < 32) hpk[p ^ 1][w * 32 + lane] = (uint8_t)f8.__x;
      pp_prev = __float2half(h_state * wpv);
    }
    // raw barrier: order LDS (h ping-pong); VMEM stays in flight.
    asm volatile("s_waitcnt lgkmcnt(0)" ::: "memory");
    __builtin_amdgcn_s_barrier();
    asm volatile("" ::: "memory");
    p ^= 1;
    zp += 256;
    zx_c = zx_n;
  }
  if (lane < 32) ppp[(size_t)(TT - 1) * UU + w * 32 + lane] = pp_prev;
}

// --------- projection: out[row] = sigmoid(sum_u ppG[row][u] + bp) ------------
__global__ __launch_bounds__(256) void proj_kernel(const __half* __restrict__ ppG,
                                                   const float* __restrict__ bp,
                                                   float* __restrict__ out) {
  int row = blockIdx.x * 4 + (threadIdx.x >> 6);
  int lane = threadIdx.x & 63;
  const ushort4* pr = (const ushort4*)(ppG + (size_t)row * UU);
  ushort4 v = pr[lane];
  __half2 a = *reinterpret_cast<__half2*>(&v.x);
  __half2 c = *reinterpret_cast<__half2*>(&v.z);
  float2 af = __half22float2(a), cf = __half22float2(c);
  float s = af.x + af.y + cf.x + cf.y;
#pragma unroll
  for (int off = 32; off > 0; off >>= 1) s += __shfl_down(s, off);
  if (lane == 0) out[row] = 1.f / (1.f + __expf(-(s + bp[0])));
}

extern "C" void kernel_launch(void* const* d_in, const int* in_sizes, int n_in,
                              void* d_out, int out_size, void* d_ws, size_t ws_size,
                              hipStream_t stream) {
  const float* x = (const float*)d_in[0];
  const float* Wfc = (const float*)d_in[1];
  const float* bfc = (const float*)d_in[2];
  const float* Wx = (const float*)d_in[3];
  const float* Wh = (const float*)d_in[4];
  const float* blstm = (const float*)d_in[5];
  const float* Wp = (const float*)d_in[6];
  const float* bp = (const float*)d_in[7];
  float* out = (float*)d_out;

  char* ws = (char*)d_ws;
  float* maskF = (float*)(ws);                                   // 128 KB
  __half* zh = (__half*)(ws + 131072);                           // 16.78 MB
  __half* zxi = (__half*)(ws + 131072 + 16777216);               // 67.1 MB
  uint8_t* whP = (uint8_t*)(ws + 131072 + 16777216 + 67108864);  // 256 KB
  __half* ppG = zh;  // zh is dead after gemm_zx; exact size match (16.78 MB)

  pack_whP<<<GG, 256, 0, stream>>>(Wh, whP);
  gemm_big<float, true, false, true><<<dim3((BB * TT) / 128, UU / 128), 256, 0, stream>>>(
      x, Wfc, bfc, zh, maskF, BB * TT, UU, FF);
  gemm_big<__half, false, true, false><<<dim3((BB * TT) / 128, GG / 128), 256, 0, stream>>>(
      zh, Wx, blstm, zxi, nullptr, BB * TT, GG, UU);
  lstm_rec<<<BB, 512, 0, stream>>>(whP, zxi, maskF, Wp, ppG);
  proj_kernel<<<(BB * TT) / 4, 256, 0, stream>>>(ppG, bp, out);
}

// Round 20
// 630.090 us; speedup vs baseline: 1.2820x; 1.0004x over previous
//
#include <hip/hip_runtime.h>
#include <hip/hip_fp16.h>
#include <hip/hip_fp8.h>
#include <cstdint>

// B=64, T=512, F=1024, U=256, G=4U=1024
#define BB 64
#define TT 512
#define FF 1024
#define UU 256
#define GG 1024

typedef _Float16 f16x8 __attribute__((ext_vector_type(8)));
typedef float f32x4 __attribute__((ext_vector_type(4)));
typedef int i32x8 __attribute__((ext_vector_type(8)));

typedef union { uint4 u4[2]; i32x8 v; } pk32;  // 32 fp8 = one K=128 MFMA operand

__device__ __forceinline__ float sigmf_(float x) { return 1.f / (1.f + __expf(-x)); }
__device__ __forceinline__ float tanhf_(float x) { return 1.f - 2.f / (1.f + __expf(2.f * x)); }

// ---- pack W_h (256x1024 f32, [u][c]) -> whP [1024 cols][256 k] fp8 e4m3 -----
__global__ __launch_bounds__(256) void pack_whP(const float* __restrict__ Wh,
                                                uint8_t* __restrict__ whP) {
  int col = blockIdx.x;   // 0..1023
  int k = threadIdx.x;    // 0..255
  __hip_fp8_e4m3 f(Wh[(size_t)k * GG + col] * 16.f);
  whP[col * 256 + k] = (uint8_t)f.__x;
}

// ------------- MFMA GEMM, 128x128 tile: C(f16) = [relu](A @ B + bias) --------
// R16-proven shape. 256 threads = 4 waves (2x2); wave-tile 64x64.
// DOMASK (fc only): while staging A (which reads ALL of x anyway), OR-reduce
// per-row nonzero-ness -> maskF. Replaces the separate mask_kernel and its
// full 134MB re-read of x. Predicate identical to reference (x pre-zeroed
// outside valid rows). blockIdx.y==0 writes (duplicate-safe anyway).
// PERM: store column ng at permuted position (ng&255)*4 + (ng>>8).
template <typename TA, bool RELU, bool PERM, bool DOMASK>
__global__ __launch_bounds__(256) void gemm_big(const TA* __restrict__ A,
                                                const float* __restrict__ Bm,
                                                const float* __restrict__ bias,
                                                __half* __restrict__ C,
                                                float* __restrict__ maskF,
                                                int M, int N, int K) {
  __shared__ _Float16 As[128][40];  // padded stride 80B
  __shared__ _Float16 Bs[128][40];  // transposed: Bs[n][k]
  __shared__ int rowflag[128];
  int tid = threadIdx.x;
  int lane = tid & 63, w = tid >> 6;
  int wm = w & 1, wn = w >> 1;
  int m0 = blockIdx.x * 128, n0 = blockIdx.y * 128;
  int fr = lane & 15, ks = lane >> 4;

  if (DOMASK && tid < 128) rowflag[tid] = 0;
  bool nz0 = false, nz1 = false, nz2 = false, nz3 = false;

  f32x4 acc[4][4];
#pragma unroll
  for (int i = 0; i < 4; ++i)
#pragma unroll
    for (int j = 0; j < 4; ++j) acc[i][j] = (f32x4){0.f, 0.f, 0.f, 0.f};

  for (int k0 = 0; k0 < K; k0 += 32) {
    {
      int r = tid >> 3, kq = (tid & 7) * 4;
#pragma unroll
      for (int i = 0; i < 4; ++i) {
        int row = r + 32 * i;
        const TA* src = A + (size_t)(m0 + row) * K + k0 + kq;
        if constexpr (sizeof(TA) == 4) {
          float4 v = *reinterpret_cast<const float4*>(src);
          if constexpr (DOMASK) {
            bool nz = (v.x != 0.f) || (v.y != 0.f) || (v.z != 0.f) || (v.w != 0.f);
            if (i == 0) nz0 |= nz;
            if (i == 1) nz1 |= nz;
            if (i == 2) nz2 |= nz;
            if (i == 3) nz3 |= nz;
          }
          union { uint2 u; _Float16 h[4]; } pk;
          pk.h[0] = (_Float16)v.x; pk.h[1] = (_Float16)v.y;
          pk.h[2] = (_Float16)v.z; pk.h[3] = (_Float16)v.w;
          *reinterpret_cast<uint2*>(&As[row][kq]) = pk.u;
        } else {
          uint2 v = *reinterpret_cast<const uint2*>(src);
          *reinterpret_cast<uint2*>(&As[row][kq]) = v;
        }
      }
      // stage B transposed: 32 k x 128 n
      int nn = tid & 127, kb = tid >> 7;  // kb in {0,1}
#pragma unroll
      for (int i = 0; i < 16; ++i) {
        int kk = kb + 2 * i;
        Bs[nn][kk] = (_Float16)Bm[(size_t)(k0 + kk) * N + n0 + nn];
      }
    }
    __syncthreads();
    f16x8 af[4], bf[4];
#pragma unroll
    for (int fm = 0; fm < 4; ++fm)
      af[fm] = *reinterpret_cast<const f16x8*>(&As[wm * 64 + fm * 16 + fr][ks * 8]);
#pragma unroll
    for (int fn = 0; fn < 4; ++fn)
      bf[fn] = *reinterpret_cast<const f16x8*>(&Bs[wn * 64 + fn * 16 + fr][ks * 8]);
#pragma unroll
    for (int fm = 0; fm < 4; ++fm)
#pragma unroll
      for (int fn = 0; fn < 4; ++fn)
        acc[fm][fn] = __builtin_amdgcn_mfma_f32_16x16x32_f16(af[fm], bf[fn], acc[fm][fn], 0, 0, 0);
    __syncthreads();
  }
  // epilogue: C/D layout col=lane&15, row=(lane>>4)*4+r  (m89-verified)
#pragma unroll
  for (int fm = 0; fm < 4; ++fm)
#pragma unroll
    for (int fn = 0; fn < 4; ++fn) {
      int mg0 = m0 + wm * 64 + fm * 16 + ks * 4;
      int ng = n0 + wn * 64 + fn * 16 + fr;
      float bv = bias[ng];
      int ngs = PERM ? ((ng & 255) * 4 + (ng >> 8)) : ng;
#pragma unroll
      for (int r = 0; r < 4; ++r) {
        float v = acc[fm][fn][r] + bv;
        if constexpr (RELU) v = fmaxf(v, 0.f);
        C[(size_t)(mg0 + r) * N + ngs] = __float2half(v);
      }
    }
  if constexpr (DOMASK) {
    int r = tid >> 3;
    if (nz0) atomicOr(&rowflag[r], 1);
    if (nz1) atomicOr(&rowflag[r + 32], 1);
    if (nz2) atomicOr(&rowflag[r + 64], 1);
    if (nz3) atomicOr(&rowflag[r + 96], 1);
    __syncthreads();
    if (tid < 128 && blockIdx.y == 0) maskF[m0 + tid] = rowflag[tid] ? 1.f : 0.f;
  }
}

// ---------------- recurrence: MX fp8 K=128 MFMA GEMV, one block/batch --------
// CHAMPION (R13/R15/R16/R18, ~505us, counters byte-stable) - final form.
// 512 threads = 8 waves = 2/SIMD; budget 256 regs/thread; W_h fp8
// all-register (128 regs); one raw barrier per step (lgkmcnt-only);
// zx gate-interleaved b64 load pipelined 1 ahead; pp export deferred,
// load-before-store issue order.
__attribute__((amdgpu_waves_per_eu(2, 2)))
__global__ void __launch_bounds__(512, 1)
lstm_rec(const uint8_t* __restrict__ whP,   // [1024][256] fp8 (x16)
         const __half* __restrict__ zxi,    // [B*T][256u][4gate] f16
         const float* __restrict__ maskF,   // [B*T]
         const float* __restrict__ Wp,      // [256]
         __half* __restrict__ ppG)          // [B*T][256] f16: h*wp per col
{
  __shared__ __align__(16) uint8_t hpk[2][256];      // fp8 h (ping-pong)
  __shared__ float mlds[TT];                         // 2KB mask row

  const int b = blockIdx.x;
  const int t = threadIdx.x;
  const int lane = t & 63, w = t >> 6;       // 8 waves
  const int fr = lane & 15, q = lane >> 4;   // q = k-slice group
  const int jj = q & 1;                      // cell-phase col-half select
  const int SC1 = 0x7F7F7F7F;                // E8M0 x1.0 scales

  const uint4* whP4 = (const uint4*)whP;  // uint4 idx = col*16 + kt*8 + q*2

  // --- preload ALL weight B-frags: kt 0..1, tile T = g*2+j (8 tiles) ---
  pk32 bfr[2][8];
#pragma unroll
  for (int kt = 0; kt < 2; ++kt)
#pragma unroll
    for (int g = 0; g < 4; ++g)
#pragma unroll
      for (int j = 0; j < 2; ++j) {
        int col = g * 256 + w * 32 + j * 16 + fr;
        bfr[kt][g * 2 + j].u4[0] = whP4[col * 16 + kt * 8 + q * 2];
        bfr[kt][g * 2 + j].u4[1] = whP4[col * 16 + kt * 8 + q * 2 + 1];
      }
#pragma unroll
  for (int kt = 0; kt < 2; ++kt)
#pragma unroll
    for (int T = 0; T < 8; ++T) {
      asm volatile("" : "+v"(bfr[kt][T].u4[0].x), "+v"(bfr[kt][T].u4[0].y),
                        "+v"(bfr[kt][T].u4[0].z), "+v"(bfr[kt][T].u4[0].w));
      asm volatile("" : "+v"(bfr[kt][T].u4[1].x), "+v"(bfr[kt][T].u4[1].y),
                        "+v"(bfr[kt][T].u4[1].z), "+v"(bfr[kt][T].u4[1].w));
    }

  if (t < 64) ((uint32_t*)hpk[0])[t] = 0u;
  mlds[t] = maskF[b * TT + t];               // 512 threads = TT exactly
  float c_state = 0.f, h_state = 0.f;
  const int ue = w * 32 + jj * 16 + fr;      // this thread's cell column
  float wpv = Wp[ue];
  __syncthreads();

  const uint2* zp = (const uint2*)(zxi + (size_t)b * TT * GG);  // 256 uint2/row
  __half* ppp = ppG + (size_t)b * TT * UU;

  uint2 zx_c = zp[ue];
  __half pp_prev = __float2half(0.f);

  int p = 0;
  for (int step = 0; step < TT; ++step) {
    // LOAD FIRST: next step's zx (vmcnt(1) wait); store stays in flight
    const uint2* zq = zp + ((step + 1 < TT) ? 256 : 0);
    uint2 zx_n = zq[ue];
    if (step > 0 && lane < 32) ppp[(size_t)(step - 1) * UU + w * 32 + lane] = pp_prev;
    float mval = mlds[step];

    // ---- MFMA phase: 8 tiles x 2 K-halves, all-register B ----
    const uint4* hp4 = (const uint4*)hpk[p];
    pk32 a0, a1;
    a0.u4[0] = hp4[q * 2];     a0.u4[1] = hp4[q * 2 + 1];
    a1.u4[0] = hp4[8 + q * 2]; a1.u4[1] = hp4[8 + q * 2 + 1];
    f32x4 d[8];
#pragma unroll
    for (int T = 0; T < 8; ++T) {
      f32x4 z = {0.f, 0.f, 0.f, 0.f};
      z = __builtin_amdgcn_mfma_scale_f32_16x16x128_f8f6f4(
          a0.v, bfr[0][T].v, z, 0, 0, 0, SC1, 0, SC1);
      d[T] = __builtin_amdgcn_mfma_scale_f32_16x16x128_f8f6f4(
          a1.v, bfr[1][T].v, z, 0, 0, 0, SC1, 0, SC1);
    }
    float s0 = d[0][0], s1 = d[1][0], s2 = d[2][0], s3 = d[3][0];
    float s4 = d[4][0], s5 = d[5][0], s6 = d[6][0], s7 = d[7][0];

    // ---- cell phase (lanes 32-63 mirror; writes guarded) ----
    {
      union { uint2 u2; __half2 h2[2]; } zz;
      zz.u2 = zx_c;
      float2 zif = __half22float2(zz.h2[0]);  // (i, f)
      float2 zgo = __half22float2(zz.h2[1]);  // (g, o)
      float gi = fmaf(jj ? s1 : s0, 0.0625f, zif.x);
      float gf = fmaf(jj ? s3 : s2, 0.0625f, zif.y);
      float gg = fmaf(jj ? s5 : s4, 0.0625f, zgo.x);
      float go = fmaf(jj ? s7 : s6, 0.0625f, zgo.y);
      float ig = sigmf_(gi);
      float fg = sigmf_(gf);
      float g_ = tanhf_(gg);
      float og = sigmf_(go);
      float cn = fg * c_state + ig * g_;
      float hn = og * tanhf_(cn);
      bool on = (mval > 0.5f);
      c_state = on ? cn : c_state;
      h_state = on ? hn : h_state;
      __hip_fp8_e4m3 f8(h_state);
      if (lane < 32) hpk[p ^ 1][w * 32 + lane] = (uint8_t)f8.__x;
      pp_prev = __float2half(h_state * wpv);
    }
    // raw barrier: order LDS (h ping-pong); VMEM stays in flight.
    asm volatile("s_waitcnt lgkmcnt(0)" ::: "memory");
    __builtin_amdgcn_s_barrier();
    asm volatile("" ::: "memory");
    p ^= 1;
    zp += 256;
    zx_c = zx_n;
  }
  if (lane < 32) ppp[(size_t)(TT - 1) * UU + w * 32 + lane] = pp_prev;
}

// --------- projection: out[row] = sigmoid(sum_u ppG[row][u] + bp) ------------
__global__ __launch_bounds__(256) void proj_kernel(const __half* __restrict__ ppG,
                                                   const float* __restrict__ bp,
                                                   float* __restrict__ out) {
  int row = blockIdx.x * 4 + (threadIdx.x >> 6);
  int lane = threadIdx.x & 63;
  const ushort4* pr = (const ushort4*)(ppG + (size_t)row * UU);
  ushort4 v = pr[lane];
  __half2 a = *reinterpret_cast<__half2*>(&v.x);
  __half2 c = *reinterpret_cast<__half2*>(&v.z);
  float2 af = __half22float2(a), cf = __half22float2(c);
  float s = af.x + af.y + cf.x + cf.y;
#pragma unroll
  for (int off = 32; off > 0; off >>= 1) s += __shfl_down(s, off);
  if (lane == 0) out[row] = 1.f / (1.f + __expf(-(s + bp[0])));
}

extern "C" void kernel_launch(void* const* d_in, const int* in_sizes, int n_in,
                              void* d_out, int out_size, void* d_ws, size_t ws_size,
                              hipStream_t stream) {
  const float* x = (const float*)d_in[0];
  const float* Wfc = (const float*)d_in[1];
  const float* bfc = (const float*)d_in[2];
  const float* Wx = (const float*)d_in[3];
  const float* Wh = (const float*)d_in[4];
  const float* blstm = (const float*)d_in[5];
  const float* Wp = (const float*)d_in[6];
  const float* bp = (const float*)d_in[7];
  float* out = (float*)d_out;

  char* ws = (char*)d_ws;
  float* maskF = (float*)(ws);                                   // 128 KB
  __half* zh = (__half*)(ws + 131072);                           // 16.78 MB
  __half* zxi = (__half*)(ws + 131072 + 16777216);               // 67.1 MB
  uint8_t* whP = (uint8_t*)(ws + 131072 + 16777216 + 67108864);  // 256 KB
  __half* ppG = zh;  // zh is dead after gemm_zx; exact size match (16.78 MB)

  pack_whP<<<GG, 256, 0, stream>>>(Wh, whP);
  gemm_big<float, true, false, true><<<dim3((BB * TT) / 128, UU / 128), 256, 0, stream>>>(
      x, Wfc, bfc, zh, maskF, BB * TT, UU, FF);
  gemm_big<__half, false, true, false><<<dim3((BB * TT) / 128, GG / 128), 256, 0, stream>>>(
      zh, Wx, blstm, zxi, nullptr, BB * TT, GG, UU);
  lstm_rec<<<BB, 512, 0, stream>>>(whP, zxi, maskF, Wp, ppG);
  proj_kernel<<<(BB * TT) / 4, 256, 0, stream>>>(ppG, bp, out);
}